// Round 2
// baseline (1681.090 us; speedup 1.0000x reference)
//
#include <hip/hip_runtime.h>
#include <stdint.h>

// Masked cumulative sum along dim=1, single-pass decoupled lookback.
//   x:    (256, 131072) float32
//   mask: (256, 131072) int32 (0/1)
//   out:  (256, 131072) float32
//
// Each row splits into 64 partitions of 2048 elems; one 256-thread block per
// partition (grid = 16384 = 2^14). Each block scans its tile in registers
// (8 elems/thread), publishes {gen|flag, aggregate} to a 64-bit state word,
// then wave 0 resolves the exclusive prefix by polling all <=63 predecessors
// in ONE 64-lane ballot window.
//
// Robustness (round-1 fixes):
//  * tick = atomicAdd(ticket); vid = tick & (GRID-1)  -> NEVER indexes OOB,
//    even if the ticket is not reset between replays (rocprof kernel replay).
//    run = tick >> 14 tags state words, so stale entries from a previous
//    un-reset run read as "not ready" instead of poisoning the lookback.
//  * ws_size / d_ws guarded; if workspace is too small we fall back to the
//    previous harness-verified row-per-block kernel (no unchecked ws writes).
//
// Forward progress (no dispatch-order assumption): a block's chain
// predecessors hold strictly lower tickets, hence were already resident when
// it spins; each block publishes its AGG with no cross-block wait, and part 0
// publishes PRE unconditionally, so every lookback terminates.

#define B_ROWS    256
#define N_COLS    131072
#define BLOCK     256
#define VPT       8
#define TILE      (BLOCK * VPT)      // 2048
#define PARTS     (N_COLS / TILE)    // 64  (<= 64: one lookback window)
#define NWAVES    (BLOCK / 64)       // 4
#define GRID      (B_ROWS * PARTS)   // 16384 = 2^14
#define GRID_LOG2 14

#define FLAG_AGG 1u
#define FLAG_PRE 2u

__device__ __forceinline__ float wave_incl_scan(float v, int lane) {
    #pragma unroll
    for (int d = 1; d < 64; d <<= 1) {
        const float y = __shfl_up(v, d, 64);
        if (lane >= d) v += y;
    }
    return v;
}

__global__ __launch_bounds__(BLOCK, 8)
void masked_cumsum_lookback(const float* __restrict__ x,
                            const int*   __restrict__ mask,
                            float*       __restrict__ out,
                            uint32_t*    __restrict__ ticket,
                            uint64_t*    __restrict__ state)
{
    __shared__ uint32_t s_tick;
    __shared__ float    s_wsum[2][NWAVES];
    __shared__ float    s_prefix;

    const int tid  = threadIdx.x;
    const int lane = tid & 63;
    const int wave = tid >> 6;

    // Virtual block id in scheduling order; gen-tag from the run counter.
    if (tid == 0) s_tick = atomicAdd(ticket, 1u);
    __syncthreads();
    const uint32_t tick   = s_tick;
    const uint32_t vid    = tick & (uint32_t)(GRID - 1);   // always in-bounds
    const uint32_t run    = tick >> GRID_LOG2;
    const uint32_t agg_hi = (run << 2) | FLAG_AGG;
    const uint32_t pre_hi = (run << 2) | FLAG_PRE;
    const int      row    = (int)(vid >> 6);               // vid / PARTS
    const int      part   = (int)(vid & (PARTS - 1));      // vid % PARTS

    const size_t base = (size_t)row * N_COLS + (size_t)part * TILE;
    const float4* __restrict__ x4 = (const float4*)(x + base);
    const int4*   __restrict__ m4 = (const int4*)(mask + base);
    float4*       __restrict__ o4 = (float4*)(out + base);

    // Load whole tile: two coalesced float4/int4 pairs per thread.
    const float4 xa = x4[tid];
    const int4   ma = m4[tid];
    const float4 xb = x4[BLOCK + tid];
    const int4   mb = m4[BLOCK + tid];

    // ---- sub-tile A: thread scan(4) + wave scan(64) ----
    const float a0 = ma.x ? xa.x : 0.0f;
    const float a1 = ma.y ? xa.y : 0.0f;
    const float a2 = ma.z ? xa.z : 0.0f;
    const float a3 = ma.w ? xa.w : 0.0f;
    const float sa0 = a0;
    const float sa1 = sa0 + a1;
    const float sa2 = sa1 + a2;
    const float sa3 = sa2 + a3;
    const float inclA  = wave_incl_scan(sa3, lane);
    const float wexclA = inclA - sa3;
    if (lane == 63) s_wsum[0][wave] = inclA;

    // ---- sub-tile B ----
    const float b0 = mb.x ? xb.x : 0.0f;
    const float b1 = mb.y ? xb.y : 0.0f;
    const float b2 = mb.z ? xb.z : 0.0f;
    const float b3 = mb.w ? xb.w : 0.0f;
    const float sb0 = b0;
    const float sb1 = sb0 + b1;
    const float sb2 = sb1 + b2;
    const float sb3 = sb2 + b3;
    const float inclB  = wave_incl_scan(sb3, lane);
    const float wexclB = inclB - sb3;
    if (lane == 63) s_wsum[1][wave] = inclB;

    __syncthreads();

    // Block combine: wave offsets + tile total (4 waves, broadcast reads).
    float offA = 0.0f, totA = 0.0f, offB = 0.0f, totB = 0.0f;
    #pragma unroll
    for (int w = 0; w < NWAVES; ++w) {
        const float va = s_wsum[0][w];
        const float vb = s_wsum[1][w];
        if (w < wave) { offA += va; offB += vb; }
        totA += va;
        totB += vb;
    }
    const float total = totA + totB;
    const float baseA = offA + wexclA;          // excl. prefix in tile, sub A
    const float baseB = totA + offB + wexclB;   // excl. prefix in tile, sub B

    uint64_t* __restrict__ strow = state + ((size_t)row << 6);

    if (part == 0) {
        if (tid == 0) {
            __hip_atomic_store(&strow[0],
                               ((uint64_t)pre_hi << 32) | (uint64_t)__float_as_uint(total),
                               __ATOMIC_RELEASE, __HIP_MEMORY_SCOPE_AGENT);
            s_prefix = 0.0f;
        }
    } else {
        // Publish aggregate ASAP (no cross-block wait before this point).
        if (tid == 0)
            __hip_atomic_store(&strow[part],
                               ((uint64_t)agg_hi << 32) | (uint64_t)__float_as_uint(total),
                               __ATOMIC_RELEASE, __HIP_MEMORY_SCOPE_AGENT);
        // Wave 0: single-window lookback. lane L polls predecessor part-1-L.
        if (wave == 0) {
            const int  pidx   = part - 1 - lane;
            const bool active = (pidx >= 0);
            float prefix;
            for (;;) {
                const uint64_t v = active
                    ? __hip_atomic_load(&strow[pidx], __ATOMIC_ACQUIRE,
                                        __HIP_MEMORY_SCOPE_AGENT)
                    : ((uint64_t)pre_hi << 32);
                const uint32_t hi    = (uint32_t)(v >> 32);
                const uint64_t ball2 = __ballot(hi == pre_hi);
                if (ball2 != 0ull) {
                    const int      d     = __ffsll((unsigned long long)ball2) - 1;
                    const uint64_t need  = (d == 0) ? 0ull : ((1ull << d) - 1ull);
                    const uint64_t ball1 = __ballot(hi == pre_hi || hi == agg_hi);
                    // lanes < d are all AGG (else d would be smaller); lane d is PRE.
                    if ((ball1 & need) == need) {
                        float contrib = (lane <= d) ? __uint_as_float((uint32_t)v) : 0.0f;
                        #pragma unroll
                        for (int o = 32; o > 0; o >>= 1)
                            contrib += __shfl_xor(contrib, o, 64);
                        prefix = contrib;
                        break;
                    }
                }
                __builtin_amdgcn_s_sleep(1);
            }
            if (lane == 0) {
                __hip_atomic_store(&strow[part],
                                   ((uint64_t)pre_hi << 32) |
                                   (uint64_t)__float_as_uint(prefix + total),
                                   __ATOMIC_RELEASE, __HIP_MEMORY_SCOPE_AGENT);
                s_prefix = prefix;
            }
        }
    }
    __syncthreads();
    const float pre = s_prefix;

    float4 ra, rb;
    ra.x = pre + baseA + sa0;
    ra.y = pre + baseA + sa1;
    ra.z = pre + baseA + sa2;
    ra.w = pre + baseA + sa3;
    rb.x = pre + baseB + sb0;
    rb.y = pre + baseB + sb1;
    rb.z = pre + baseB + sb2;
    rb.w = pre + baseB + sb3;
    o4[tid]         = ra;
    o4[BLOCK + tid] = rb;
}

// ---------------------------------------------------------------------------
// Fallback: previous harness-verified kernel (314 us) — row-per-block, no
// workspace. Used only if d_ws is absent or too small for the lookback state.
// ---------------------------------------------------------------------------
#define FB_BLOCK  1024
#define FB_VEC    4
#define FB_TILE   (FB_BLOCK * FB_VEC)   // 4096
#define FB_NTILES (N_COLS / FB_TILE)    // 32
#define FB_NWAVES (FB_BLOCK / 64)       // 16

__global__ __launch_bounds__(FB_BLOCK)
void masked_cumsum_fallback(const float* __restrict__ x,
                            const int* __restrict__ mask,
                            float* __restrict__ out) {
    __shared__ float waveSums[2][FB_NWAVES];

    const int row  = blockIdx.x;
    const int tid  = threadIdx.x;
    const int lane = tid & 63;
    const int wave = tid >> 6;

    const size_t rowBase = (size_t)row * N_COLS;
    const float4* __restrict__ x4 = (const float4*)(x + rowBase);
    const int4*   __restrict__ m4 = (const int4*)(mask + rowBase);
    float4*       __restrict__ o4 = (float4*)(out + rowBase);

    float carry = 0.0f;
    float4 xv = x4[tid];
    int4   mv = m4[tid];

    for (int t = 0; t < FB_NTILES; ++t) {
        const float4 cx = xv;
        const int4   cm = mv;
        if (t + 1 < FB_NTILES) {
            const int nidx = (t + 1) * FB_BLOCK + tid;
            xv = x4[nidx];
            mv = m4[nidx];
        }
        const float v0 = cm.x ? cx.x : 0.0f;
        const float v1 = cm.y ? cx.y : 0.0f;
        const float v2 = cm.z ? cx.z : 0.0f;
        const float v3 = cm.w ? cx.w : 0.0f;
        const float s0 = v0;
        const float s1 = s0 + v1;
        const float s2 = s1 + v2;
        const float s3 = s2 + v3;
        const float tsum = s3;

        float incl = tsum;
        #pragma unroll
        for (int d = 1; d < 64; d <<= 1) {
            const float y = __shfl_up(incl, d, 64);
            if (lane >= d) incl += y;
        }
        const float waveExcl = incl - tsum;

        if (lane == 63) waveSums[t & 1][wave] = incl;
        __syncthreads();

        float waveOff = 0.0f, tileTot = 0.0f;
        #pragma unroll
        for (int w = 0; w < FB_NWAVES; ++w) {
            const float s = waveSums[t & 1][w];
            if (w < wave) waveOff += s;
            tileTot += s;
        }

        const float base = carry + waveOff + waveExcl;
        float4 r;
        r.x = base + s0;
        r.y = base + s1;
        r.z = base + s2;
        r.w = base + s3;
        o4[t * FB_BLOCK + tid] = r;

        carry += tileTot;
    }
}

extern "C" void kernel_launch(void* const* d_in, const int* in_sizes, int n_in,
                              void* d_out, int out_size, void* d_ws, size_t ws_size,
                              hipStream_t stream) {
    const float* x    = (const float*)d_in[0];
    const int*   mask = (const int*)d_in[1];
    float*       out  = (float*)d_out;
    (void)in_sizes; (void)n_in; (void)out_size;

    const size_t need = 256 + (size_t)GRID * sizeof(uint64_t);  // ~128.3 KB
    if (d_ws != nullptr && ws_size >= need) {
        uint32_t* ticket = (uint32_t*)d_ws;
        uint64_t* state  = (uint64_t*)((char*)d_ws + 256);
        // Zero ticket+state (guards first-use garbage; gen-tagging makes the
        // kernel correct even if a replay skips this node).
        hipMemsetAsync(d_ws, 0, need, stream);
        masked_cumsum_lookback<<<GRID, BLOCK, 0, stream>>>(x, mask, out, ticket, state);
    } else {
        masked_cumsum_fallback<<<B_ROWS, FB_BLOCK, 0, stream>>>(x, mask, out);
    }
}

// Round 4
// 1516.779 us; speedup vs baseline: 1.1083x; 1.1083x over previous
//
#include <hip/hip_runtime.h>
#include <stdint.h>

// Masked cumulative sum along dim=1, single-pass decoupled lookback.
//   x:    (256, 131072) float32
//   mask: (256, 131072) int32 (0/1)
//   out:  (256, 131072) float32
//
// Round-4: identical to round-3 except the non-temporal stores use a native
// clang ext_vector float4 (HIP's float4 struct is rejected by
// __builtin_nontemporal_store).
//
// Key design (round-3 theory): lookback polling uses RELAXED agent-scope
// atomic loads, not ACQUIRE. On gfx950, agent-acquire emits
// `s_waitcnt vmcnt(0)` + `buffer_inv` PER POLL, invalidating the XCD's L1/L2
// continuously (round 2 measured: 184 GB/s, VALUBusy 1.1%). The polled 64-bit
// word packs {gen|flag, value}; its own atomicity provides all the consistency
// we consume. Relaxed agent loads still carry sc1 (read the coherence point),
// so release-published values are observed across XCDs. Publishers keep
// RELEASE stores (one per block). Capped-exponential s_sleep backoff cuts
// residual poll traffic; non-temporal output stores keep the 134 MB write
// stream from evicting x/mask in L2/L3.
//
// Robustness (harness-verified in round 2):
//  * vid = tick & (GRID-1) never indexes OOB even without ticket reset;
//    run-generation tag makes stale state words read as "not ready".
//  * ws_size/d_ws guarded; fallback to the old row-per-block kernel if the
//    workspace is too small. No unchecked workspace writes.
// Forward progress without dispatch-order assumptions: chain predecessors
// hold strictly lower tickets (already resident), publish AGG with no
// cross-block wait; part 0 publishes PRE unconditionally.

#define B_ROWS    256
#define N_COLS    131072
#define BLOCK     256
#define VPT       8
#define TILE      (BLOCK * VPT)      // 2048
#define PARTS     (N_COLS / TILE)    // 64  (<= 64: one lookback window)
#define NWAVES    (BLOCK / 64)       // 4
#define GRID      (B_ROWS * PARTS)   // 16384 = 2^14
#define GRID_LOG2 14

#define FLAG_AGG 1u
#define FLAG_PRE 2u

typedef float nativef4 __attribute__((ext_vector_type(4)));

__device__ __forceinline__ float wave_incl_scan(float v, int lane) {
    #pragma unroll
    for (int d = 1; d < 64; d <<= 1) {
        const float y = __shfl_up(v, d, 64);
        if (lane >= d) v += y;
    }
    return v;
}

__global__ __launch_bounds__(BLOCK, 8)
void masked_cumsum_lookback(const float* __restrict__ x,
                            const int*   __restrict__ mask,
                            float*       __restrict__ out,
                            uint32_t*    __restrict__ ticket,
                            uint64_t*    __restrict__ state)
{
    __shared__ uint32_t s_tick;
    __shared__ float    s_wsum[2][NWAVES];
    __shared__ float    s_prefix;

    const int tid  = threadIdx.x;
    const int lane = tid & 63;
    const int wave = tid >> 6;

    // Virtual block id in scheduling order; gen-tag from the run counter.
    if (tid == 0) s_tick = atomicAdd(ticket, 1u);
    __syncthreads();
    const uint32_t tick   = s_tick;
    const uint32_t vid    = tick & (uint32_t)(GRID - 1);   // always in-bounds
    const uint32_t run    = tick >> GRID_LOG2;
    const uint32_t agg_hi = (run << 2) | FLAG_AGG;
    const uint32_t pre_hi = (run << 2) | FLAG_PRE;
    const int      row    = (int)(vid >> 6);               // vid / PARTS
    const int      part   = (int)(vid & (PARTS - 1));      // vid % PARTS

    const size_t base = (size_t)row * N_COLS + (size_t)part * TILE;
    const float4* __restrict__ x4 = (const float4*)(x + base);
    const int4*   __restrict__ m4 = (const int4*)(mask + base);
    nativef4*     __restrict__ o4 = (nativef4*)(out + base);

    // Load whole tile: two coalesced float4/int4 pairs per thread.
    const float4 xa = x4[tid];
    const int4   ma = m4[tid];
    const float4 xb = x4[BLOCK + tid];
    const int4   mb = m4[BLOCK + tid];

    // ---- sub-tile A: thread scan(4) + wave scan(64) ----
    const float a0 = ma.x ? xa.x : 0.0f;
    const float a1 = ma.y ? xa.y : 0.0f;
    const float a2 = ma.z ? xa.z : 0.0f;
    const float a3 = ma.w ? xa.w : 0.0f;
    const float sa0 = a0;
    const float sa1 = sa0 + a1;
    const float sa2 = sa1 + a2;
    const float sa3 = sa2 + a3;
    const float inclA  = wave_incl_scan(sa3, lane);
    const float wexclA = inclA - sa3;
    if (lane == 63) s_wsum[0][wave] = inclA;

    // ---- sub-tile B ----
    const float b0 = mb.x ? xb.x : 0.0f;
    const float b1 = mb.y ? xb.y : 0.0f;
    const float b2 = mb.z ? xb.z : 0.0f;
    const float b3 = mb.w ? xb.w : 0.0f;
    const float sb0 = b0;
    const float sb1 = sb0 + b1;
    const float sb2 = sb1 + b2;
    const float sb3 = sb2 + b3;
    const float inclB  = wave_incl_scan(sb3, lane);
    const float wexclB = inclB - sb3;
    if (lane == 63) s_wsum[1][wave] = inclB;

    __syncthreads();

    // Block combine: wave offsets + tile total (4 waves, broadcast reads).
    float offA = 0.0f, totA = 0.0f, offB = 0.0f, totB = 0.0f;
    #pragma unroll
    for (int w = 0; w < NWAVES; ++w) {
        const float va = s_wsum[0][w];
        const float vb = s_wsum[1][w];
        if (w < wave) { offA += va; offB += vb; }
        totA += va;
        totB += vb;
    }
    const float total = totA + totB;
    const float baseA = offA + wexclA;          // excl. prefix in tile, sub A
    const float baseB = totA + offB + wexclB;   // excl. prefix in tile, sub B

    uint64_t* __restrict__ strow = state + ((size_t)row << 6);

    if (part == 0) {
        if (tid == 0) {
            __hip_atomic_store(&strow[0],
                               ((uint64_t)pre_hi << 32) | (uint64_t)__float_as_uint(total),
                               __ATOMIC_RELEASE, __HIP_MEMORY_SCOPE_AGENT);
            s_prefix = 0.0f;
        }
    } else {
        // Publish aggregate ASAP (no cross-block wait before this point).
        if (tid == 0)
            __hip_atomic_store(&strow[part],
                               ((uint64_t)agg_hi << 32) | (uint64_t)__float_as_uint(total),
                               __ATOMIC_RELEASE, __HIP_MEMORY_SCOPE_AGENT);
        // Wave 0: single-window lookback. lane L polls predecessor part-1-L.
        // RELAXED polls: the packed 64-bit word is self-consistent; relaxed
        // agent loads still read the coherence point (sc1) but emit NO
        // buffer_inv -> no L2-invalidate storm (round-2 lesson).
        if (wave == 0) {
            const int  pidx   = part - 1 - lane;
            const bool active = (pidx >= 0);
            float prefix;
            int   backoff = 0;
            for (;;) {
                const uint64_t v = active
                    ? __hip_atomic_load(&strow[pidx], __ATOMIC_RELAXED,
                                        __HIP_MEMORY_SCOPE_AGENT)
                    : ((uint64_t)pre_hi << 32);
                const uint32_t hi    = (uint32_t)(v >> 32);
                const uint64_t ball2 = __ballot(hi == pre_hi);
                if (ball2 != 0ull) {
                    const int      d     = __ffsll((unsigned long long)ball2) - 1;
                    const uint64_t need  = (d == 0) ? 0ull : ((1ull << d) - 1ull);
                    const uint64_t ball1 = __ballot(hi == pre_hi || hi == agg_hi);
                    // lanes < d are all AGG (else d would be smaller); lane d is PRE.
                    if ((ball1 & need) == need) {
                        float contrib = (lane <= d) ? __uint_as_float((uint32_t)v) : 0.0f;
                        #pragma unroll
                        for (int o = 32; o > 0; o >>= 1)
                            contrib += __shfl_xor(contrib, o, 64);
                        prefix = contrib;
                        break;
                    }
                }
                // Capped exponential backoff: 64..1024 cycles.
                switch (backoff) {
                    case 0:  __builtin_amdgcn_s_sleep(1);  backoff = 1; break;
                    case 1:  __builtin_amdgcn_s_sleep(2);  backoff = 2; break;
                    case 2:  __builtin_amdgcn_s_sleep(4);  backoff = 3; break;
                    case 3:  __builtin_amdgcn_s_sleep(8);  backoff = 4; break;
                    default: __builtin_amdgcn_s_sleep(16);             break;
                }
            }
            if (lane == 0) {
                __hip_atomic_store(&strow[part],
                                   ((uint64_t)pre_hi << 32) |
                                   (uint64_t)__float_as_uint(prefix + total),
                                   __ATOMIC_RELEASE, __HIP_MEMORY_SCOPE_AGENT);
                s_prefix = prefix;
            }
        }
    }
    __syncthreads();
    const float pre = s_prefix;

    nativef4 ra, rb;
    ra.x = pre + baseA + sa0;
    ra.y = pre + baseA + sa1;
    ra.z = pre + baseA + sa2;
    ra.w = pre + baseA + sa3;
    rb.x = pre + baseB + sb0;
    rb.y = pre + baseB + sb1;
    rb.z = pre + baseB + sb2;
    rb.w = pre + baseB + sb3;
    // Non-temporal: out is write-once, never re-read by this kernel; keep it
    // from evicting x/mask in L2/L3.
    __builtin_nontemporal_store(ra, &o4[tid]);
    __builtin_nontemporal_store(rb, &o4[BLOCK + tid]);
}

// ---------------------------------------------------------------------------
// Fallback: previous harness-verified kernel (314 us) — row-per-block, no
// workspace. Used only if d_ws is absent or too small for the lookback state.
// ---------------------------------------------------------------------------
#define FB_BLOCK  1024
#define FB_VEC    4
#define FB_TILE   (FB_BLOCK * FB_VEC)   // 4096
#define FB_NTILES (N_COLS / FB_TILE)    // 32
#define FB_NWAVES (FB_BLOCK / 64)       // 16

__global__ __launch_bounds__(FB_BLOCK)
void masked_cumsum_fallback(const float* __restrict__ x,
                            const int* __restrict__ mask,
                            float* __restrict__ out) {
    __shared__ float waveSums[2][FB_NWAVES];

    const int row  = blockIdx.x;
    const int tid  = threadIdx.x;
    const int lane = tid & 63;
    const int wave = tid >> 6;

    const size_t rowBase = (size_t)row * N_COLS;
    const float4* __restrict__ x4 = (const float4*)(x + rowBase);
    const int4*   __restrict__ m4 = (const int4*)(mask + rowBase);
    float4*       __restrict__ o4 = (float4*)(out + rowBase);

    float carry = 0.0f;
    float4 xv = x4[tid];
    int4   mv = m4[tid];

    for (int t = 0; t < FB_NTILES; ++t) {
        const float4 cx = xv;
        const int4   cm = mv;
        if (t + 1 < FB_NTILES) {
            const int nidx = (t + 1) * FB_BLOCK + tid;
            xv = x4[nidx];
            mv = m4[nidx];
        }
        const float v0 = cm.x ? cx.x : 0.0f;
        const float v1 = cm.y ? cx.y : 0.0f;
        const float v2 = cm.z ? cx.z : 0.0f;
        const float v3 = cm.w ? cx.w : 0.0f;
        const float s0 = v0;
        const float s1 = s0 + v1;
        const float s2 = s1 + v2;
        const float s3 = s2 + v3;
        const float tsum = s3;

        float incl = tsum;
        #pragma unroll
        for (int d = 1; d < 64; d <<= 1) {
            const float y = __shfl_up(incl, d, 64);
            if (lane >= d) incl += y;
        }
        const float waveExcl = incl - tsum;

        if (lane == 63) waveSums[t & 1][wave] = incl;
        __syncthreads();

        float waveOff = 0.0f, tileTot = 0.0f;
        #pragma unroll
        for (int w = 0; w < FB_NWAVES; ++w) {
            const float s = waveSums[t & 1][w];
            if (w < wave) waveOff += s;
            tileTot += s;
        }

        const float base = carry + waveOff + waveExcl;
        float4 r;
        r.x = base + s0;
        r.y = base + s1;
        r.z = base + s2;
        r.w = base + s3;
        o4[t * FB_BLOCK + tid] = r;

        carry += tileTot;
    }
}

extern "C" void kernel_launch(void* const* d_in, const int* in_sizes, int n_in,
                              void* d_out, int out_size, void* d_ws, size_t ws_size,
                              hipStream_t stream) {
    const float* x    = (const float*)d_in[0];
    const int*   mask = (const int*)d_in[1];
    float*       out  = (float*)d_out;
    (void)in_sizes; (void)n_in; (void)out_size;

    const size_t need = 256 + (size_t)GRID * sizeof(uint64_t);  // ~128.3 KB
    if (d_ws != nullptr && ws_size >= need) {
        uint32_t* ticket = (uint32_t*)d_ws;
        uint64_t* state  = (uint64_t*)((char*)d_ws + 256);
        // Zero ticket+state (guards first-use garbage; gen-tagging makes the
        // kernel correct even if a replay skips this node).
        (void)hipMemsetAsync(d_ws, 0, need, stream);
        masked_cumsum_lookback<<<GRID, BLOCK, 0, stream>>>(x, mask, out, ticket, state);
    } else {
        masked_cumsum_fallback<<<B_ROWS, FB_BLOCK, 0, stream>>>(x, mask, out);
    }
}

// Round 5
// 411.978 us; speedup vs baseline: 4.0805x; 3.6817x over previous
//
#include <hip/hip_runtime.h>
#include <stdint.h>

// Masked cumulative sum along dim=1, single-pass decoupled lookback.
//   x:    (256, 131072) float32
//   mask: (256, 131072) int32 (0/1)
//   out:  (256, 131072) float32
//
// Round-5 change (single variable): ALL state-word atomics are RELAXED.
// Round 2 (acquire polls + release publishes): 1485 us.
// Round 4 (relaxed polls + release publishes): 1317 us.  -> polls weren't it.
// An agent-scope RELEASE store on gfx950 emits s_waitcnt vmcnt(0) +
// buffer_wbl2 (XCD L2 dirty writeback) per publish; 32768 publishes x
// continuously re-dirtied L2 (resident blocks' 48 KB output streams) =
// serialized flush storm: waves past their loads, spinning while publishes
// crawl (89% occupancy, 1.3% VALUBusy, 5% HBM). The packed 64-bit
// {gen|flag, value} word carries its payload INSIDE the atomic word - no
// other memory is communicated - so relaxed agent atomics (sc1: write-through
// to / read from the coherence point, cross-XCD visible) are sufficient.
// Zero wbl2 / inv / vmcnt(0) drains remain in the protocol.
//
// Robustness (harness-verified): vid = tick & (GRID-1) never indexes OOB even
// without ticket reset; run-generation tag makes stale state words read as
// "not ready"; ws_size/d_ws guarded with fallback kernel.
// Forward progress without dispatch-order assumptions: chain predecessors
// hold strictly lower tickets (already resident/finished), publish AGG with
// no cross-block wait; part 0 publishes PRE unconditionally.

#define B_ROWS    256
#define N_COLS    131072
#define BLOCK     256
#define VPT       8
#define TILE      (BLOCK * VPT)      // 2048
#define PARTS     (N_COLS / TILE)    // 64  (<= 64: one lookback window)
#define NWAVES    (BLOCK / 64)       // 4
#define GRID      (B_ROWS * PARTS)   // 16384 = 2^14
#define GRID_LOG2 14

#define FLAG_AGG 1u
#define FLAG_PRE 2u

typedef float nativef4 __attribute__((ext_vector_type(4)));

__device__ __forceinline__ float wave_incl_scan(float v, int lane) {
    #pragma unroll
    for (int d = 1; d < 64; d <<= 1) {
        const float y = __shfl_up(v, d, 64);
        if (lane >= d) v += y;
    }
    return v;
}

__global__ __launch_bounds__(BLOCK, 8)
void masked_cumsum_lookback(const float* __restrict__ x,
                            const int*   __restrict__ mask,
                            float*       __restrict__ out,
                            uint32_t*    __restrict__ ticket,
                            uint64_t*    __restrict__ state)
{
    __shared__ uint32_t s_tick;
    __shared__ float    s_wsum[2][NWAVES];
    __shared__ float    s_prefix;

    const int tid  = threadIdx.x;
    const int lane = tid & 63;
    const int wave = tid >> 6;

    // Virtual block id in scheduling order; gen-tag from the run counter.
    if (tid == 0) s_tick = atomicAdd(ticket, 1u);
    __syncthreads();
    const uint32_t tick   = s_tick;
    const uint32_t vid    = tick & (uint32_t)(GRID - 1);   // always in-bounds
    const uint32_t run    = tick >> GRID_LOG2;
    const uint32_t agg_hi = (run << 2) | FLAG_AGG;
    const uint32_t pre_hi = (run << 2) | FLAG_PRE;
    const int      row    = (int)(vid >> 6);               // vid / PARTS
    const int      part   = (int)(vid & (PARTS - 1));      // vid % PARTS

    const size_t base = (size_t)row * N_COLS + (size_t)part * TILE;
    const float4* __restrict__ x4 = (const float4*)(x + base);
    const int4*   __restrict__ m4 = (const int4*)(mask + base);
    nativef4*     __restrict__ o4 = (nativef4*)(out + base);

    // Load whole tile: two coalesced float4/int4 pairs per thread.
    const float4 xa = x4[tid];
    const int4   ma = m4[tid];
    const float4 xb = x4[BLOCK + tid];
    const int4   mb = m4[BLOCK + tid];

    // ---- sub-tile A: thread scan(4) + wave scan(64) ----
    const float a0 = ma.x ? xa.x : 0.0f;
    const float a1 = ma.y ? xa.y : 0.0f;
    const float a2 = ma.z ? xa.z : 0.0f;
    const float a3 = ma.w ? xa.w : 0.0f;
    const float sa0 = a0;
    const float sa1 = sa0 + a1;
    const float sa2 = sa1 + a2;
    const float sa3 = sa2 + a3;
    const float inclA  = wave_incl_scan(sa3, lane);
    const float wexclA = inclA - sa3;
    if (lane == 63) s_wsum[0][wave] = inclA;

    // ---- sub-tile B ----
    const float b0 = mb.x ? xb.x : 0.0f;
    const float b1 = mb.y ? xb.y : 0.0f;
    const float b2 = mb.z ? xb.z : 0.0f;
    const float b3 = mb.w ? xb.w : 0.0f;
    const float sb0 = b0;
    const float sb1 = sb0 + b1;
    const float sb2 = sb1 + b2;
    const float sb3 = sb2 + b3;
    const float inclB  = wave_incl_scan(sb3, lane);
    const float wexclB = inclB - sb3;
    if (lane == 63) s_wsum[1][wave] = inclB;

    __syncthreads();

    // Block combine: wave offsets + tile total (4 waves, broadcast reads).
    float offA = 0.0f, totA = 0.0f, offB = 0.0f, totB = 0.0f;
    #pragma unroll
    for (int w = 0; w < NWAVES; ++w) {
        const float va = s_wsum[0][w];
        const float vb = s_wsum[1][w];
        if (w < wave) { offA += va; offB += vb; }
        totA += va;
        totB += vb;
    }
    const float total = totA + totB;
    const float baseA = offA + wexclA;          // excl. prefix in tile, sub A
    const float baseB = totA + offB + wexclB;   // excl. prefix in tile, sub B

    uint64_t* __restrict__ strow = state + ((size_t)row << 6);

    if (part == 0) {
        if (tid == 0) {
            __hip_atomic_store(&strow[0],
                               ((uint64_t)pre_hi << 32) | (uint64_t)__float_as_uint(total),
                               __ATOMIC_RELAXED, __HIP_MEMORY_SCOPE_AGENT);
            s_prefix = 0.0f;
        }
    } else {
        // Publish aggregate ASAP (no cross-block wait before this point).
        // RELAXED: value rides inside the atomic word; no wbl2/drain.
        if (tid == 0)
            __hip_atomic_store(&strow[part],
                               ((uint64_t)agg_hi << 32) | (uint64_t)__float_as_uint(total),
                               __ATOMIC_RELAXED, __HIP_MEMORY_SCOPE_AGENT);
        // Wave 0: single-window lookback. lane L polls predecessor part-1-L.
        if (wave == 0) {
            const int  pidx   = part - 1 - lane;
            const bool active = (pidx >= 0);
            float prefix;
            int   backoff = 0;
            for (;;) {
                const uint64_t v = active
                    ? __hip_atomic_load(&strow[pidx], __ATOMIC_RELAXED,
                                        __HIP_MEMORY_SCOPE_AGENT)
                    : ((uint64_t)pre_hi << 32);
                const uint32_t hi    = (uint32_t)(v >> 32);
                const uint64_t ball2 = __ballot(hi == pre_hi);
                if (ball2 != 0ull) {
                    const int      d     = __ffsll((unsigned long long)ball2) - 1;
                    const uint64_t need  = (d == 0) ? 0ull : ((1ull << d) - 1ull);
                    const uint64_t ball1 = __ballot(hi == pre_hi || hi == agg_hi);
                    // lanes < d are all AGG (else d would be smaller); lane d is PRE.
                    if ((ball1 & need) == need) {
                        float contrib = (lane <= d) ? __uint_as_float((uint32_t)v) : 0.0f;
                        #pragma unroll
                        for (int o = 32; o > 0; o >>= 1)
                            contrib += __shfl_xor(contrib, o, 64);
                        prefix = contrib;
                        break;
                    }
                }
                // Short backoff: observe publishes quickly (64..256 cycles).
                switch (backoff) {
                    case 0:  __builtin_amdgcn_s_sleep(1); backoff = 1; break;
                    case 1:  __builtin_amdgcn_s_sleep(2); backoff = 2; break;
                    default: __builtin_amdgcn_s_sleep(4);              break;
                }
            }
            if (lane == 0) {
                __hip_atomic_store(&strow[part],
                                   ((uint64_t)pre_hi << 32) |
                                   (uint64_t)__float_as_uint(prefix + total),
                                   __ATOMIC_RELAXED, __HIP_MEMORY_SCOPE_AGENT);
                s_prefix = prefix;
            }
        }
    }
    __syncthreads();
    const float pre = s_prefix;

    nativef4 ra, rb;
    ra.x = pre + baseA + sa0;
    ra.y = pre + baseA + sa1;
    ra.z = pre + baseA + sa2;
    ra.w = pre + baseA + sa3;
    rb.x = pre + baseB + sb0;
    rb.y = pre + baseB + sb1;
    rb.z = pre + baseB + sb2;
    rb.w = pre + baseB + sb3;
    // Non-temporal: out is write-once, never re-read by this kernel; keep it
    // from evicting x/mask in L2/L3.
    __builtin_nontemporal_store(ra, &o4[tid]);
    __builtin_nontemporal_store(rb, &o4[BLOCK + tid]);
}

// ---------------------------------------------------------------------------
// Fallback: previous harness-verified kernel (314 us) — row-per-block, no
// workspace. Used only if d_ws is absent or too small for the lookback state.
// ---------------------------------------------------------------------------
#define FB_BLOCK  1024
#define FB_VEC    4
#define FB_TILE   (FB_BLOCK * FB_VEC)   // 4096
#define FB_NTILES (N_COLS / FB_TILE)    // 32
#define FB_NWAVES (FB_BLOCK / 64)       // 16

__global__ __launch_bounds__(FB_BLOCK)
void masked_cumsum_fallback(const float* __restrict__ x,
                            const int* __restrict__ mask,
                            float* __restrict__ out) {
    __shared__ float waveSums[2][FB_NWAVES];

    const int row  = blockIdx.x;
    const int tid  = threadIdx.x;
    const int lane = tid & 63;
    const int wave = tid >> 6;

    const size_t rowBase = (size_t)row * N_COLS;
    const float4* __restrict__ x4 = (const float4*)(x + rowBase);
    const int4*   __restrict__ m4 = (const int4*)(mask + rowBase);
    float4*       __restrict__ o4 = (float4*)(out + rowBase);

    float carry = 0.0f;
    float4 xv = x4[tid];
    int4   mv = m4[tid];

    for (int t = 0; t < FB_NTILES; ++t) {
        const float4 cx = xv;
        const int4   cm = mv;
        if (t + 1 < FB_NTILES) {
            const int nidx = (t + 1) * FB_BLOCK + tid;
            xv = x4[nidx];
            mv = m4[nidx];
        }
        const float v0 = cm.x ? cx.x : 0.0f;
        const float v1 = cm.y ? cx.y : 0.0f;
        const float v2 = cm.z ? cx.z : 0.0f;
        const float v3 = cm.w ? cx.w : 0.0f;
        const float s0 = v0;
        const float s1 = s0 + v1;
        const float s2 = s1 + v2;
        const float s3 = s2 + v3;
        const float tsum = s3;

        float incl = tsum;
        #pragma unroll
        for (int d = 1; d < 64; d <<= 1) {
            const float y = __shfl_up(incl, d, 64);
            if (lane >= d) incl += y;
        }
        const float waveExcl = incl - tsum;

        if (lane == 63) waveSums[t & 1][wave] = incl;
        __syncthreads();

        float waveOff = 0.0f, tileTot = 0.0f;
        #pragma unroll
        for (int w = 0; w < FB_NWAVES; ++w) {
            const float s = waveSums[t & 1][w];
            if (w < wave) waveOff += s;
            tileTot += s;
        }

        const float base = carry + waveOff + waveExcl;
        float4 r;
        r.x = base + s0;
        r.y = base + s1;
        r.z = base + s2;
        r.w = base + s3;
        o4[t * FB_BLOCK + tid] = r;

        carry += tileTot;
    }
}

extern "C" void kernel_launch(void* const* d_in, const int* in_sizes, int n_in,
                              void* d_out, int out_size, void* d_ws, size_t ws_size,
                              hipStream_t stream) {
    const float* x    = (const float*)d_in[0];
    const int*   mask = (const int*)d_in[1];
    float*       out  = (float*)d_out;
    (void)in_sizes; (void)n_in; (void)out_size;

    const size_t need = 256 + (size_t)GRID * sizeof(uint64_t);  // ~128.3 KB
    if (d_ws != nullptr && ws_size >= need) {
        uint32_t* ticket = (uint32_t*)d_ws;
        uint64_t* state  = (uint64_t*)((char*)d_ws + 256);
        // Zero ticket+state (guards first-use garbage; gen-tagging makes the
        // kernel correct even if a replay skips this node).
        (void)hipMemsetAsync(d_ws, 0, need, stream);
        masked_cumsum_lookback<<<GRID, BLOCK, 0, stream>>>(x, mask, out, ticket, state);
    } else {
        masked_cumsum_fallback<<<B_ROWS, FB_BLOCK, 0, stream>>>(x, mask, out);
    }
}

// Round 7
// 347.740 us; speedup vs baseline: 4.8343x; 1.1847x over previous
//
#include <hip/hip_runtime.h>
#include <stdint.h>

// Masked cumulative sum along dim=1 — two-kernel reduce-then-scan.
//   x:    (256, 131072) float32
//   mask: (256, 131072) int32 (0/1)
//   out:  (256, 131072) float32
//
// Round-7: resubmission of round-6 (bench infra failed twice; no kernel data,
// no compile error; source has no constructible fault path — all indices
// statically bounded, no atomics/spin/memset, workspace guarded).
//
// Design rationale (from round-5 counters): single-pass lookback at 217 us
// showed occupancy 85% / HBM 16% / VALU 7% — resident blocks parked in the
// poll loop waiting on co-resident predecessors' loads, ~19 us latency
// overhead per 2048-block generation. Two streaming kernels have ZERO
// inter-block dependencies: no spin, no atomics, no memset, no ticket.
//
//   Kernel A: per-partition masked totals (16384 x 2048-elem tiles).
//             Reads 268 MB, writes 64 KB. Pure streaming.
//   Kernel B: re-reads x+mask (L3-hot: A just touched all 268 MB; LLC=256MB),
//             reads its row's 64 totals (256 B, L2-hot), scans in-block,
//             writes out with NON-TEMPORAL stores so the 134 MB write stream
//             does not evict the inputs.
//
// Kernel boundary on the same stream guarantees A's totals are visible to B
// (runtime fences at dispatch boundaries) — no XCD-coherence hazard, no
// dispatch-order assumption. Workspace: 64 KB plain data, written-before-read
// every launch; replay-safe with no re-arm. ws_size guarded; fallback to the
// old harness-verified row-per-block kernel if the workspace is too small.

#define B_ROWS 256
#define N_COLS 131072
#define BLOCK  256
#define VPT    8
#define TILE   (BLOCK * VPT)      // 2048
#define PARTS  (N_COLS / TILE)    // 64
#define NWAVES (BLOCK / 64)       // 4
#define GRID   (B_ROWS * PARTS)   // 16384

typedef float nativef4 __attribute__((ext_vector_type(4)));

// ---------------------------------------------------------------------------
// Kernel A: per-partition masked totals.
// ---------------------------------------------------------------------------
__global__ __launch_bounds__(BLOCK, 8)
void masked_tile_totals(const float* __restrict__ x,
                        const int*   __restrict__ mask,
                        float*       __restrict__ totals)
{
    __shared__ float s_wsum[NWAVES];

    const int tid  = threadIdx.x;
    const int lane = tid & 63;
    const int wave = tid >> 6;
    const int bid  = blockIdx.x;
    const int row  = bid >> 6;              // bid / PARTS
    const int part = bid & (PARTS - 1);     // bid % PARTS

    const size_t base = (size_t)row * N_COLS + (size_t)part * TILE;
    const float4* __restrict__ x4 = (const float4*)(x + base);
    const int4*   __restrict__ m4 = (const int4*)(mask + base);

    const float4 xa = x4[tid];
    const int4   ma = m4[tid];
    const float4 xb = x4[BLOCK + tid];
    const int4   mb = m4[BLOCK + tid];

    float s = (ma.x ? xa.x : 0.0f) + (ma.y ? xa.y : 0.0f)
            + (ma.z ? xa.z : 0.0f) + (ma.w ? xa.w : 0.0f)
            + (mb.x ? xb.x : 0.0f) + (mb.y ? xb.y : 0.0f)
            + (mb.z ? xb.z : 0.0f) + (mb.w ? xb.w : 0.0f);

    #pragma unroll
    for (int o = 32; o > 0; o >>= 1)
        s += __shfl_xor(s, o, 64);

    if (lane == 0) s_wsum[wave] = s;
    __syncthreads();
    if (tid == 0)
        totals[bid] = s_wsum[0] + s_wsum[1] + s_wsum[2] + s_wsum[3];
}

// ---------------------------------------------------------------------------
// Kernel B: in-tile scan + direct prefix from totals.
// ---------------------------------------------------------------------------
__device__ __forceinline__ float wave_incl_scan(float v, int lane) {
    #pragma unroll
    for (int d = 1; d < 64; d <<= 1) {
        const float y = __shfl_up(v, d, 64);
        if (lane >= d) v += y;
    }
    return v;
}

__global__ __launch_bounds__(BLOCK, 8)
void masked_cumsum_scan(const float* __restrict__ x,
                        const int*   __restrict__ mask,
                        const float* __restrict__ totals,
                        float*       __restrict__ out)
{
    __shared__ float s_wsum[2][NWAVES];
    __shared__ float s_prefix;

    const int tid  = threadIdx.x;
    const int lane = tid & 63;
    const int wave = tid >> 6;
    const int bid  = blockIdx.x;
    const int row  = bid >> 6;
    const int part = bid & (PARTS - 1);

    const size_t base = (size_t)row * N_COLS + (size_t)part * TILE;
    const float4* __restrict__ x4 = (const float4*)(x + base);
    const int4*   __restrict__ m4 = (const int4*)(mask + base);
    nativef4*     __restrict__ o4 = (nativef4*)(out + base);

    // Tile loads (L3-hot from kernel A) + totals load (wave 0, L2-hot).
    const float4 xa = x4[tid];
    const int4   ma = m4[tid];
    const float4 xb = x4[BLOCK + tid];
    const int4   mb = m4[BLOCK + tid];
    const float  tl = (wave == 0) ? totals[(row << 6) + lane] : 0.0f;

    // ---- sub-tile A: thread scan(4) + wave scan(64) ----
    const float a0 = ma.x ? xa.x : 0.0f;
    const float a1 = ma.y ? xa.y : 0.0f;
    const float a2 = ma.z ? xa.z : 0.0f;
    const float a3 = ma.w ? xa.w : 0.0f;
    const float sa0 = a0;
    const float sa1 = sa0 + a1;
    const float sa2 = sa1 + a2;
    const float sa3 = sa2 + a3;
    const float inclA  = wave_incl_scan(sa3, lane);
    const float wexclA = inclA - sa3;
    if (lane == 63) s_wsum[0][wave] = inclA;

    // ---- sub-tile B ----
    const float b0 = mb.x ? xb.x : 0.0f;
    const float b1 = mb.y ? xb.y : 0.0f;
    const float b2 = mb.z ? xb.z : 0.0f;
    const float b3 = mb.w ? xb.w : 0.0f;
    const float sb0 = b0;
    const float sb1 = sb0 + b1;
    const float sb2 = sb1 + b2;
    const float sb3 = sb2 + b3;
    const float inclB  = wave_incl_scan(sb3, lane);
    const float wexclB = inclB - sb3;
    if (lane == 63) s_wsum[1][wave] = inclB;

    // ---- cross-partition prefix: sum of this row's totals[0..part-1] ----
    if (wave == 0) {
        float c = (lane < part) ? tl : 0.0f;
        #pragma unroll
        for (int o = 32; o > 0; o >>= 1)
            c += __shfl_xor(c, o, 64);
        if (lane == 0) s_prefix = c;
    }
    __syncthreads();

    // Block combine: wave offsets + sub-tile-A total.
    float offA = 0.0f, totA = 0.0f, offB = 0.0f;
    #pragma unroll
    for (int w = 0; w < NWAVES; ++w) {
        const float va = s_wsum[0][w];
        const float vb = s_wsum[1][w];
        if (w < wave) { offA += va; offB += vb; }
        totA += va;
    }
    const float pre   = s_prefix;
    const float baseA = pre + offA + wexclA;
    const float baseB = pre + totA + offB + wexclB;

    nativef4 ra, rb;
    ra.x = baseA + sa0;
    ra.y = baseA + sa1;
    ra.z = baseA + sa2;
    ra.w = baseA + sa3;
    rb.x = baseB + sb0;
    rb.y = baseB + sb1;
    rb.z = baseB + sb2;
    rb.w = baseB + sb3;
    // Non-temporal: write-once stream; don't evict L3-resident x/mask.
    __builtin_nontemporal_store(ra, &o4[tid]);
    __builtin_nontemporal_store(rb, &o4[BLOCK + tid]);
}

// ---------------------------------------------------------------------------
// Fallback: previous harness-verified kernel (314 us) — row-per-block, no
// workspace. Used only if d_ws is absent or too small for the totals buffer.
// ---------------------------------------------------------------------------
#define FB_BLOCK  1024
#define FB_VEC    4
#define FB_TILE   (FB_BLOCK * FB_VEC)   // 4096
#define FB_NTILES (N_COLS / FB_TILE)    // 32
#define FB_NWAVES (FB_BLOCK / 64)       // 16

__global__ __launch_bounds__(FB_BLOCK)
void masked_cumsum_fallback(const float* __restrict__ x,
                            const int* __restrict__ mask,
                            float* __restrict__ out) {
    __shared__ float waveSums[2][FB_NWAVES];

    const int row  = blockIdx.x;
    const int tid  = threadIdx.x;
    const int lane = tid & 63;
    const int wave = tid >> 6;

    const size_t rowBase = (size_t)row * N_COLS;
    const float4* __restrict__ x4 = (const float4*)(x + rowBase);
    const int4*   __restrict__ m4 = (const int4*)(mask + rowBase);
    float4*       __restrict__ o4 = (float4*)(out + rowBase);

    float carry = 0.0f;
    float4 xv = x4[tid];
    int4   mv = m4[tid];

    for (int t = 0; t < FB_NTILES; ++t) {
        const float4 cx = xv;
        const int4   cm = mv;
        if (t + 1 < FB_NTILES) {
            const int nidx = (t + 1) * FB_BLOCK + tid;
            xv = x4[nidx];
            mv = m4[nidx];
        }
        const float v0 = cm.x ? cx.x : 0.0f;
        const float v1 = cm.y ? cx.y : 0.0f;
        const float v2 = cm.z ? cx.z : 0.0f;
        const float v3 = cm.w ? cx.w : 0.0f;
        const float s0 = v0;
        const float s1 = s0 + v1;
        const float s2 = s1 + v2;
        const float s3 = s2 + v3;
        const float tsum = s3;

        float incl = tsum;
        #pragma unroll
        for (int d = 1; d < 64; d <<= 1) {
            const float y = __shfl_up(incl, d, 64);
            if (lane >= d) incl += y;
        }
        const float waveExcl = incl - tsum;

        if (lane == 63) waveSums[t & 1][wave] = incl;
        __syncthreads();

        float waveOff = 0.0f, tileTot = 0.0f;
        #pragma unroll
        for (int w = 0; w < FB_NWAVES; ++w) {
            const float s = waveSums[t & 1][w];
            if (w < wave) waveOff += s;
            tileTot += s;
        }

        const float base = carry + waveOff + waveExcl;
        float4 r;
        r.x = base + s0;
        r.y = base + s1;
        r.z = base + s2;
        r.w = base + s3;
        o4[t * FB_BLOCK + tid] = r;

        carry += tileTot;
    }
}

extern "C" void kernel_launch(void* const* d_in, const int* in_sizes, int n_in,
                              void* d_out, int out_size, void* d_ws, size_t ws_size,
                              hipStream_t stream) {
    const float* x    = (const float*)d_in[0];
    const int*   mask = (const int*)d_in[1];
    float*       out  = (float*)d_out;
    (void)in_sizes; (void)n_in; (void)out_size;

    const size_t need = (size_t)GRID * sizeof(float);   // 64 KB
    if (d_ws != nullptr && ws_size >= need) {
        float* totals = (float*)d_ws;
        // A writes totals; same-stream ordering makes them visible to B.
        masked_tile_totals<<<GRID, BLOCK, 0, stream>>>(x, mask, totals);
        masked_cumsum_scan<<<GRID, BLOCK, 0, stream>>>(x, mask, totals, out);
    } else {
        masked_cumsum_fallback<<<B_ROWS, FB_BLOCK, 0, stream>>>(x, mask, out);
    }
}